// Round 7
// baseline (214.535 us; speedup 1.0000x reference)
//
#include <hip/hip_runtime.h>
#include <cfloat>

#define DIM 2048
#define NE  64

typedef _Float16 half8 __attribute__((ext_vector_type(8)));
typedef float    f32x4 __attribute__((ext_vector_type(4)));

struct Split { _Float16 hi, lo; };

// Split fp32 into fp16 hi + fp16 lo where x ≈ hi + lo/2048.
// hi clamped to 0 below fp16-min-normal so no denormal reaches the MFMA.
__device__ __forceinline__ Split split_f32(float x) {
    Split r;
    float h32;
    if (__builtin_fabsf(x) >= 6.103515625e-05f) {
        r.hi = (_Float16)x;          // v_cvt_f16_f32 (RTN)
        h32  = (float)r.hi;
    } else {
        r.hi = (_Float16)0.0f; h32 = 0.0f;
    }
    r.lo = (_Float16)((x - h32) * 2048.0f);
    return r;
}

// Pre-kernel: split W [64][2048] into fragment-ordered fp16 hi/lo in ws.
// hi element index: (sg*4 + nt)*64 + lane ; lo at +16384 (half8 units).
// Lane l of chunk (sg,nt) holds W[nt*16 + (l&15)][sg*32 + (l>>4)*8 + 0..7].
__global__ void wsplit_kernel(const float* __restrict__ W, _Float16* __restrict__ wsb) {
    int t    = blockIdx.x * 256 + threadIdx.x;   // 0..16383
    int lane = t & 63;
    int nt   = (t >> 6) & 3;
    int sg   = t >> 8;                           // k32-step 0..63
    int e    = nt * 16 + (lane & 15);
    int k    = sg * 32 + (lane >> 4) * 8;
    const float* wp = W + (size_t)e * DIM + k;
    half8 hi, lo;
    #pragma unroll
    for (int j = 0; j < 8; ++j) {
        Split s = split_f32(wp[j]);
        hi[j] = s.hi; lo[j] = s.lo;
    }
    ((half8*)wsb)[(size_t)((sg * 4 + nt) * 64 + lane)]         = hi;
    ((half8*)wsb)[(size_t)(16384 + (sg * 4 + nt) * 64 + lane)] = lo;
}

// Main: 1024 blocks x 256 thr (4 waves). Block = 16 tokens; wave w = K-quarter w
// (16 K32-steps). A prefetched 3 steps ahead (covers ~900cyc HBM-miss latency),
// B (L2-resident ws) double-buffered 1 ahead.
template <bool USE_WS>
__launch_bounds__(256, 3)
__global__ void gate_mfma_kernel(const float* __restrict__ x,
                                 const float* __restrict__ W,
                                 const float* __restrict__ b,
                                 float* __restrict__ out,
                                 const _Float16* __restrict__ wsb)
{
    __shared__ float sgrid[4][16][68];   // [k-quarter][token][expert], padded

    const int tid  = threadIdx.x;
    const int lane = tid & 63;
    const int wave = tid >> 6;           // k-quarter 0..3
    const int tokb = blockIdx.x * 16;
    const int row  = tokb + (lane & 15);

    const float* aptr = x + (size_t)row * DIM + wave * 512 + (lane >> 4) * 8;
    const half8* wb   = (const half8*)wsb;
    const int bbase = wave * 16 * 256 + lane;   // half8-element index base

    f32x4 acch[4], accc[4];
    #pragma unroll
    for (int nt = 0; nt < 4; ++nt) {
        acch[nt] = (f32x4){0.f, 0.f, 0.f, 0.f};
        accc[nt] = (f32x4){0.f, 0.f, 0.f, 0.f};
    }

    half8 Bh[2][4], Bl[2][4];
    f32x4 A0[4], A1[4];

    // ---- preload: A steps 0..2, B step 0 ----
    #pragma unroll
    for (int p = 0; p < 3; ++p) {
        A0[p] = *(const f32x4*)(aptr + p * 32);
        A1[p] = *(const f32x4*)(aptr + p * 32 + 4);
    }
    if (USE_WS) {
        #pragma unroll
        for (int nt = 0; nt < 4; ++nt) {
            Bh[0][nt] = wb[bbase + nt * 64];
            Bl[0][nt] = wb[16384 + bbase + nt * 64];
        }
    }

    #pragma unroll
    for (int s = 0; s < 16; ++s) {
        const int cur = s & 1, nxt = cur ^ 1;
        const int ac  = s & 3;

        // ---- issue future loads first: A for s+3, B for s+1 ----
        if (s + 3 < 16) {
            const int an = (s + 3) & 3;
            A0[an] = *(const f32x4*)(aptr + (s + 3) * 32);
            A1[an] = *(const f32x4*)(aptr + (s + 3) * 32 + 4);
        }
        if (USE_WS && (s + 1 < 16)) {
            const int o = bbase + (s + 1) * 256;
            #pragma unroll
            for (int nt = 0; nt < 4; ++nt) {
                Bh[nxt][nt] = wb[o + nt * 64];
                Bl[nxt][nt] = wb[16384 + o + nt * 64];
            }
        }

        // ---- split current A ----
        half8 Ah, Al;
        #pragma unroll
        for (int j = 0; j < 4; ++j) {
            Split sp = split_f32(A0[ac][j]);
            Ah[j] = sp.hi; Al[j] = sp.lo;
        }
        #pragma unroll
        for (int j = 0; j < 4; ++j) {
            Split sp = split_f32(A1[ac][j]);
            Ah[4 + j] = sp.hi; Al[4 + j] = sp.lo;
        }

        // ---- B for current step ----
        half8 Bhc[4], Blc[4];
        if (USE_WS) {
            #pragma unroll
            for (int nt = 0; nt < 4; ++nt) { Bhc[nt] = Bh[cur][nt]; Blc[nt] = Bl[cur][nt]; }
        } else {
            const int sg = wave * 16 + s;
            #pragma unroll
            for (int nt = 0; nt < 4; ++nt) {
                const float* wp = W + (size_t)(nt * 16 + (lane & 15)) * DIM
                                    + sg * 32 + (lane >> 4) * 8;
                #pragma unroll
                for (int j = 0; j < 8; ++j) {
                    Split sp = split_f32(wp[j]);
                    Bhc[nt][j] = sp.hi; Blc[nt][j] = sp.lo;
                }
            }
        }

        // ---- 12 MFMAs ----
        #pragma unroll
        for (int nt = 0; nt < 4; ++nt)
            acch[nt] = __builtin_amdgcn_mfma_f32_16x16x32_f16(Ah, Bhc[nt], acch[nt], 0, 0, 0);
        #pragma unroll
        for (int nt = 0; nt < 4; ++nt)
            accc[nt] = __builtin_amdgcn_mfma_f32_16x16x32_f16(Al, Bhc[nt], accc[nt], 0, 0, 0);
        #pragma unroll
        for (int nt = 0; nt < 4; ++nt)
            accc[nt] = __builtin_amdgcn_mfma_f32_16x16x32_f16(Ah, Blc[nt], accc[nt], 0, 0, 0);
    }

    // ---- partial scores to LDS: D row=(lane>>4)*4+r (token), col=lane&15 (expert) ----
    #pragma unroll
    for (int nt = 0; nt < 4; ++nt)
        #pragma unroll
        for (int r = 0; r < 4; ++r) {
            int tl = (lane >> 4) * 4 + r;
            int e  = nt * 16 + (lane & 15);
            sgrid[wave][tl][e] = acch[nt][r] + accc[nt][r] * (1.0f / 2048.0f);
        }
    __syncthreads();

    // ---- per-token top-2 + renormalized softmax (proven epilogue) ----
    const float bias = b[lane];
    #pragma unroll
    for (int tt = 0; tt < 4; ++tt) {
        const int t = wave * 4 + tt;
        float s = sgrid[0][t][lane] + sgrid[1][t][lane]
                + sgrid[2][t][lane] + sgrid[3][t][lane] + bias;

        float v = s; int i = lane;
        #pragma unroll
        for (int off = 32; off > 0; off >>= 1) {
            float ov = __shfl_xor(v, off, 64);
            int   oi = __shfl_xor(i, off, 64);
            if (ov > v || (ov == v && oi < i)) { v = ov; i = oi; }
        }
        const float m1 = v; const int i1 = i;

        float s2 = (lane == i1) ? -FLT_MAX : s;
        v = s2; i = lane;
        #pragma unroll
        for (int off = 32; off > 0; off >>= 1) {
            float ov = __shfl_xor(v, off, 64);
            int   oi = __shfl_xor(i, off, 64);
            if (ov > v || (ov == v && oi < i)) { v = ov; i = oi; }
        }
        const float m2 = v; const int i2 = i;

        const float e_  = __expf(m2 - m1);
        const float inv = 1.f / (1.f + e_);
        const float outv = (lane == i1) ? inv : ((lane == i2) ? e_ * inv : 0.f);
        out[(size_t)(tokb + t) * NE + lane] = outv;
    }
}

extern "C" void kernel_launch(void* const* d_in, const int* in_sizes, int n_in,
                              void* d_out, int out_size, void* d_ws, size_t ws_size,
                              hipStream_t stream) {
    const float* x = (const float*)d_in[0];
    const float* W = (const float*)d_in[1];
    const float* b = (const float*)d_in[2];
    float* out = (float*)d_out;

    const int n_tokens = in_sizes[0] / DIM;      // 16384
    dim3 grid(n_tokens / 16);                    // 1024 blocks
    dim3 block(256);                             // 4 waves

    if (ws_size >= 524288) {
        wsplit_kernel<<<dim3(64), dim3(256), 0, stream>>>(W, (_Float16*)d_ws);
        gate_mfma_kernel<true><<<grid, block, 0, stream>>>(x, W, b, out, (const _Float16*)d_ws);
    } else {
        gate_mfma_kernel<false><<<grid, block, 0, stream>>>(x, W, b, out, nullptr);
    }
}